// Round 22
// baseline (1259.921 us; speedup 1.0000x reference)
//
#include <hip/hip_runtime.h>
#include <hip/hip_bf16.h>

#define BATCH 512
#define SEQ   500
#define BS    (BATCH*SEQ)     // 256000
#define MEM   64
#define DK    128
#define DV    256
#define FC    128
#define KS    16              // scan steps per LDS stage

typedef float f32x4 __attribute__((ext_vector_type(4)));
typedef float f32x2 __attribute__((ext_vector_type(2)));
typedef unsigned int u32x4 __attribute__((ext_vector_type(4)));
typedef unsigned int u32x2 __attribute__((ext_vector_type(2)));
typedef unsigned short u16x8 __attribute__((ext_vector_type(8)));
typedef __bf16 bf16x8 __attribute__((ext_vector_type(8)));

__device__ __forceinline__ float bf2f(unsigned short u){ return __uint_as_float(((unsigned)u)<<16); }
__device__ __forceinline__ unsigned short f2bfu(float x){
  unsigned u = __float_as_uint(x);
  return (unsigned short)((u + 0x7FFFu + ((u>>16)&1u)) >> 16);  // RNE
}
__device__ __forceinline__ float sigf(float x){ return 1.f/(1.f+__expf(-x)); }
__device__ __forceinline__ float tanh_fast(float x){ return 2.f/(1.f+__expf(-2.f*x)) - 1.f; }

// 3-hop in-row shift-add: after shr 1,2,4 lane q==7 holds its 8-lane group sum.
#define DPP3(r) { \
  asm("v_add_f32_dpp %0, %0, %0 row_shr:1 row_mask:0xf bank_mask:0xf bound_ctrl:0" : "+v"(r)); \
  asm("v_add_f32_dpp %0, %0, %0 row_shr:2 row_mask:0xf bank_mask:0xf bound_ctrl:0" : "+v"(r)); \
  asm("v_add_f32_dpp %0, %0, %0 row_shr:4 row_mask:0xf bank_mask:0xf bound_ctrl:0" : "+v"(r)); \
}

__device__ __forceinline__ float ldF(const void* p, long i, int f32m){
  return f32m ? ((const float*)p)[i] : bf2f(((const unsigned short*)p)[i]);
}
__device__ __forceinline__ int ldI(const int* p, long i, int i64m){
  return i64m ? p[2*i] : p[i];   // little-endian low word of int64
}
__device__ __forceinline__ void st8(unsigned short* dst, const void* src, long i, int f32m){
  if (f32m){
    const float* q = (const float*)src + i;
    f32x4 a = *(const f32x4*)q;
    f32x4 b = *(const f32x4*)(q+4);
    u16x8 o;
    o[0]=f2bfu(a[0]); o[1]=f2bfu(a[1]); o[2]=f2bfu(a[2]); o[3]=f2bfu(a[3]);
    o[4]=f2bfu(b[0]); o[5]=f2bfu(b[1]); o[6]=f2bfu(b[2]); o[7]=f2bfu(b[3]);
    *(u16x8*)dst = o;
  } else {
    *(u16x8*)dst = *(const u16x8*)((const unsigned short*)src + i);
  }
}
__device__ __forceinline__ void stOut(void* p, long i, float x, int f32m){
  if (f32m) ((float*)p)[i] = x;
  else ((unsigned short*)p)[i] = f2bfu(x);
}

// direct global->register MFMA fragment load (8 elems at element-offset i)
__device__ __forceinline__ bf16x8 ldfrag(const void* p, long i, int f32m){
  if (f32m){
    const float* q = (const float*)p + i;
    f32x4 a = *(const f32x4*)q;
    f32x4 b = *(const f32x4*)(q+4);
    u32x4 o;
    asm("v_cvt_pk_bf16_f32 %0, %1, %2" : "=v"(o[0]) : "v"(a[0]), "v"(a[1]));
    asm("v_cvt_pk_bf16_f32 %0, %1, %2" : "=v"(o[1]) : "v"(a[2]), "v"(a[3]));
    asm("v_cvt_pk_bf16_f32 %0, %1, %2" : "=v"(o[2]) : "v"(b[0]), "v"(b[1]));
    asm("v_cvt_pk_bf16_f32 %0, %1, %2" : "=v"(o[3]) : "v"(b[2]), "v"(b[3]));
    return __builtin_bit_cast(bf16x8, o);
  } else {
    return __builtin_bit_cast(bf16x8, *(const u16x8*)((const unsigned short*)p + i));
  }
}

// ---------------- K0: dtype detection + accum zero ----------------
__global__ void k_detect(const unsigned short* __restrict__ km, const int* __restrict__ qa,
                         int* __restrict__ flags, float* __restrict__ accum){
  int t = threadIdx.x;            // 64 threads, one wave
  if (t < 2) accum[t] = 0.f;
  unsigned short u = km[2*t];     // even u16 halves of key_memory
  int e = (u >> 7) & 0xFF;
  bool sane = (e==0) || (e>=100 && e<=140);
  unsigned long long sm = __ballot(sane);
  unsigned long long zm = __ballot(qa[2*t+1] == 0);
  if (t == 0){
    flags[0] = (__popcll(sm) < 48) ? 1 : 0;               // 1 = f32 float buffers
    flags[1] = (zm == 0xFFFFFFFFFFFFFFFFull) ? 1 : 0;     // 1 = int64 index buffers
  }
}

// ---------------- K1: cw = softmax(q_e @ key^T) ----------------
__global__ __launch_bounds__(256, 2) void k_cw(const int* __restrict__ qd,
    const void* __restrict__ qW, const void* __restrict__ keym,
    float* __restrict__ cw, const int* __restrict__ flags){
  const int f32m = flags[0], i64m = flags[1];
  __shared__ float keyT[DK][MEM];
  int t = threadIdx.x;
  for (int i=t;i<MEM*DK;i+=256){ int m=i&63, k=i>>6; keyT[k][m] = ldF(keym, (long)m*DK+k, f32m); }
  __syncthreads();
  long row = (long)blockIdx.x*256 + t;
  int qid = ldI(qd, row, i64m);
  long qb = (long)qid*DK;
  f32x4 A[16];
  #pragma unroll
  for (int g=0;g<16;g++) A[g] = (f32x4){0.f,0.f,0.f,0.f};
  for (int kk=0;kk<DK;kk+=8){
    float qv[8];
    if (f32m){
      const float* qp = (const float*)qW + qb + kk;
      f32x4 a=*(const f32x4*)qp, b=*(const f32x4*)(qp+4);
      qv[0]=a[0];qv[1]=a[1];qv[2]=a[2];qv[3]=a[3];qv[4]=b[0];qv[5]=b[1];qv[6]=b[2];qv[7]=b[3];
    } else {
      u16x8 u = *(const u16x8*)((const unsigned short*)qW + qb + kk);
      #pragma unroll
      for (int j=0;j<8;j++) qv[j]=bf2f(u[j]);
    }
    #pragma unroll
    for (int j=0;j<8;j++){
      float q = qv[j];
      #pragma unroll
      for (int g=0;g<16;g++){
        f32x4 kv = *(const f32x4*)&keyT[kk+j][g*4];
        f32x4 a = A[g];
        a[0]=fmaf(q,kv[0],a[0]); a[1]=fmaf(q,kv[1],a[1]);
        a[2]=fmaf(q,kv[2],a[2]); a[3]=fmaf(q,kv[3],a[3]);
        A[g]=a;
      }
    }
  }
  float mx = -1e30f;
  #pragma unroll
  for (int g=0;g<16;g++){
    f32x4 a = A[g];
    mx = fmaxf(mx, fmaxf(fmaxf(a[0],a[1]), fmaxf(a[2],a[3])));
  }
  float sum = 0.f;
  #pragma unroll
  for (int g=0;g<16;g++){
    f32x4 a = A[g];
    a[0]=__expf(a[0]-mx); a[1]=__expf(a[1]-mx); a[2]=__expf(a[2]-mx); a[3]=__expf(a[3]-mx);
    sum += (a[0]+a[1])+(a[2]+a[3]);
    A[g]=a;
  }
  float inv = 1.f/sum;
  float* outp = cw + row*MEM;
  #pragma unroll
  for (int g=0;g<16;g++){
    f32x4 a = A[g];
    f32x4 v = { a[0]*inv, a[1]*inv, a[2]*inv, a[3]*inv };
    *(f32x4*)(outp + g*4) = v;
  }
}

// ---------------- K2 (per-chunk): [erase|add] GEMM — barrier-free, LDS-free ----------------
// Fragments loaded straight from global (L1/L2 serve k-loop revisits). Row base pointers are
// loop-invariant; k0 advances by immediate offset. Zero barriers -> waves fully independent.
__global__ __launch_bounds__(256, 2) void k_ea(const int* __restrict__ qad, long row0,
    const void* __restrict__ qaW, const void* __restrict__ eW, const void* __restrict__ ebias,
    const void* __restrict__ aW, const void* __restrict__ abias,
    unsigned short* __restrict__ ea, const int* __restrict__ flags, int nwg){
  const int f32m = flags[0], i64m = flags[1];
  int g = blockIdx.x;
  // bijective XCD-chunk swizzle (m204)
  int x = g & 7, idx = g >> 3;
  int qq = nwg >> 3, rr = nwg & 7;
  int base = (x < rr) ? x*(qq+1) : rr*(qq+1) + (x-rr)*qq;
  int orig = base + idx;
  int bm = orig >> 2, bn = orig & 3;

  int t = threadIdx.x;
  int lane = t & 63, wid = t >> 6;
  int wr = wid >> 1, wc = wid & 1;
  int kq = (lane >> 4) * 8;            // k-slice within fragment

  // loop-invariant row bases (element offsets)
  long aRow[4];
  #pragma unroll
  for (int i=0;i<4;i++){
    int row = wr*64 + i*16 + (lane&15);
    int qid = ldI(qad, row0 + (long)bm*128 + row, i64m);
    aRow[i] = (long)qid*DV + kq;
  }
  const void* Bp = wc ? aW : eW;       // wc=0 -> erase weights, wc=1 -> add weights
  long bRow[4];
  #pragma unroll
  for (int n=0;n<4;n++) bRow[n] = (long)(64*bn + n*16 + (lane&15))*DV + kq;

  f32x4 acc[4][4] = {};
  #pragma unroll
  for (int k0=0;k0<DV;k0+=32){
    bf16x8 af[4], bfr[4];
    #pragma unroll
    for (int i=0;i<4;i++) af[i]  = ldfrag(qaW, aRow[i] + k0, f32m);
    #pragma unroll
    for (int n=0;n<4;n++) bfr[n] = ldfrag(Bp, bRow[n] + k0, f32m);
    #pragma unroll
    for (int i=0;i<4;i++)
      #pragma unroll
      for (int n=0;n<4;n++)
        acc[i][n] = __builtin_amdgcn_mfma_f32_16x16x32_bf16(af[i], bfr[n], acc[i][n],0,0,0);
  }
  #pragma unroll
  for (int i=0;i<4;i++)
    #pragma unroll
    for (int n=0;n<4;n++){
      int cc = n*16 + (lane&15);          // col within the 64-wide strip
      int gcol = 64*bn + cc;              // global er/ad column
      float bias = wc ? ldF(abias,gcol,f32m) : ldF(ebias,gcol,f32m);
      int dcol = 2*gcol + wc;             // interleaved (er,ad) pair layout
      #pragma unroll
      for (int rix=0;rix<4;rix++){
        long rowg = (long)bm*128 + wr*64 + i*16 + (lane>>4)*4 + rix;
        float v = acc[i][n][rix] + bias;
        float o = wc ? tanh_fast(v) : sigf(v);
        ea[rowg*(2*DV) + dcol] = f2bfu(o);
      }
    }
}

// ---------------- K3 (per-chunk): scan — d-half split, LDS-staged, scalar FMA + DPP ----------------
#define SCAN_STEP2(srel) { \
  f32x4 W0 = *(const f32x4*)(wb + (srel)*MEM); \
  f32x4 W1 = *(const f32x4*)(wb + (srel)*MEM + 4); \
  u32x2 uu = *(const u32x2*)(eb + (srel)*128); \
  float er0 = __uint_as_float(uu[0] << 16); \
  float ad0 = __uint_as_float(uu[0] & 0xFFFF0000u); \
  float er1 = __uint_as_float(uu[1] << 16); \
  float ad1 = __uint_as_float(uu[1] & 0xFFFF0000u); \
  float ra0=0.f, ra1=0.f, rb0=0.f, rb1=0.f; \
  _Pragma("unroll") \
  for (int j=0; j<8; j++){ \
    float w = (j<4) ? W0[j] : W1[j-4]; \
    if (j & 1) ra1 = fmaf(w, MA[j], ra1); else ra0 = fmaf(w, MA[j], ra0); \
    float ta = fmaf(MA[j], er0, -ad0); \
    MA[j] = fmaf(-w, ta, MA[j]); \
    if (j & 1) rb1 = fmaf(w, MB[j], rb1); else rb0 = fmaf(w, MB[j], rb0); \
    float tb = fmaf(MB[j], er1, -ad1); \
    MB[j] = fmaf(-w, tb, MB[j]); \
  } \
  float r0 = ra0 + ra1; \
  float r1 = rb0 + rb1; \
  DPP3(r0); \
  DPP3(r1); \
  if (q == 7){ \
    unsigned pk; \
    asm("v_cvt_pk_bf16_f32 %0, %1, %2" : "=v"(pk) : "v"(r0), "v"(r1)); \
    rdu[(srel)*128] = pk; \
  } \
}

__global__ __launch_bounds__(512, 4) void k_scan(const float* __restrict__ cw,
    const unsigned short* __restrict__ ea, const void* __restrict__ initm,
    unsigned short* __restrict__ rdout, const int* __restrict__ flags){
  const int f32m = flags[0];
  __shared__ float        w_lds[2][KS][MEM];     // 8 KB
  __shared__ unsigned int ea_lds[2][KS][128];    // 16 KB (this block's d-half)
  int b = blockIdx.x, y = blockIdx.y;
  int t = threadIdx.x;          // 0..511
  int q = t & 7;
  int dp = t >> 3;              // 0..63
  int d0 = y*128 + 2*dp;
  int m0 = q * 8;

  float MA[8], MB[8];
  #pragma unroll
  for (int g=0; g<8; g++){
    MA[g] = ldF(initm, (long)(m0+g)*DV + d0,   f32m);
    MB[g] = ldF(initm, (long)(m0+g)*DV + d0+1, f32m);
  }

  const float* cwb = cw + (long)b*SEQ*MEM;
  const unsigned int* epb = (const unsigned int*)(ea + (long)b*SEQ*(2*DV)) + y*128;  // row stride 256 u32
  unsigned int* rdu = (unsigned int*)(rdout + (long)b*SEQ*DV) + y*64 + dp;           // row = 128 u32

  {
    f32x2 wreg = *(const f32x2*)(cwb + 2*t);
    u32x4 ereg = *(const u32x4*)(epb + (t>>5)*256 + 4*(t&31));
    ((f32x2*)(&w_lds[0][0][0]))[t] = wreg;
    ((u32x4*)(&ea_lds[0][0][0]))[t] = ereg;
  }
  __syncthreads();

  int cur = 0;
  for (int st = 0; st < 31; st++){
    f32x2 wnext = *(const f32x2*)(cwb + (st+1)*KS*MEM + 2*t);
    u32x4 enext = *(const u32x4*)(epb + ((st+1)*KS + (t>>5))*256 + 4*(t&31));

    const float* wb        = &w_lds[cur][0][0] + m0;
    const unsigned int* eb = &ea_lds[cur][0][0] + 2*dp;
    #pragma unroll
    for (int srel=0; srel<KS; srel++){
      SCAN_STEP2(srel);
    }
    ((f32x2*)(&w_lds[cur^1][0][0]))[t] = wnext;
    ((u32x4*)(&ea_lds[cur^1][0][0]))[t] = enext;
    rdu += KS*128;
    __syncthreads();
    cur ^= 1;
  }
  {
    const float* wb        = &w_lds[cur][0][0] + m0;
    const unsigned int* eb = &ea_lds[cur][0][0] + 2*dp;
    #pragma unroll
    for (int srel=0; srel<4; srel++){
      SCAN_STEP2(srel);
    }
  }
}

// ---------------- K4 (per-chunk): h = tanh([reads|q_e] @ rW^T + rb); logit; BCE ----------------
// r15 measured-best: separate As/Bs/hs, (256,2)
__global__ __launch_bounds__(256, 2) void k_pred(const int* __restrict__ qd, long row0,
    const void* __restrict__ qW, const unsigned short* __restrict__ rds,
    const void* __restrict__ rW, const void* __restrict__ rb,
    const void* __restrict__ pW, const void* __restrict__ pb,
    const void* __restrict__ target,
    void* __restrict__ out, float* __restrict__ accum,
    const int* __restrict__ flags){
  const int f32m = flags[0], i64m = flags[1];
  __shared__ unsigned short As[128][40];
  __shared__ unsigned short Bs[128][40];
  __shared__ unsigned short hs[128][136];
  __shared__ int rid[128];
  int t = threadIdx.x;
  int bm = blockIdx.x;
  if (t<128) rid[t] = ldI(qd, row0 + (long)bm*128+t, i64m);
  int lane=t&63, wid=t>>6, wr=wid>>1, wc=wid&1;
  f32x4 acc[4][4] = {};
  for (int k0=0;k0<(DV+DK);k0+=32){
    __syncthreads();
    #pragma unroll
    for (int j=0;j<2;j++){
      int c=t*2+j, r=c>>2, ko=(c&3)*8;
      if (k0 < DV) st8(&As[r][ko], rds, ((long)bm*128+r)*DV + k0+ko, 0);
      else         st8(&As[r][ko], qW, (long)rid[r]*DK + (k0-DV)+ko, f32m);
      st8(&Bs[r][ko], rW, (long)r*(DV+DK) + k0+ko, f32m);
    }
    __syncthreads();
    bf16x8 af[4], bfr[4];
    #pragma unroll
    for (int i=0;i<4;i++){
      af[i]  = __builtin_bit_cast(bf16x8, *(const u16x8*)&As[wr*64+i*16+(lane&15)][(lane>>4)*8]);
      bfr[i] = __builtin_bit_cast(bf16x8, *(const u16x8*)&Bs[wc*64+i*16+(lane&15)][(lane>>4)*8]);
    }
    #pragma unroll
    for (int i=0;i<4;i++)
      #pragma unroll
      for (int n=0;n<4;n++)
        acc[i][n] = __builtin_amdgcn_mfma_f32_16x16x32_bf16(af[i], bfr[n], acc[i][n],0,0,0);
  }
  #pragma unroll
  for (int i=0;i<4;i++)
    #pragma unroll
    for (int n=0;n<4;n++){
      int col = wc*64 + n*16 + (lane&15);
      float bias = ldF(rb, col, f32m);
      #pragma unroll
      for (int rix=0;rix<4;rix++){
        int rowl = wr*64 + i*16 + (lane>>4)*4 + rix;
        hs[rowl][col] = f2bfu(tanh_fast(acc[i][n][rix] + bias));
      }
    }
  __syncthreads();
  float bces = 0.f, cnts = 0.f;
  if (t < 128){
    float lg = ldF(pb, 0, f32m);
    #pragma unroll
    for (int cc=0;cc<FC;cc++) lg = fmaf(bf2f(hs[t][cc]), ldF(pW, cc, f32m), lg);
    long rowg = row0 + (long)bm*128 + t;
    float tg = ldF(target, rowg, f32m);
    bool mask = tg >= 0.f;
    float e = __expf(-fabsf(lg));
    float bce = fmaxf(lg, 0.f) - lg*tg + __logf(1.f + e);
    bces = mask ? bce : 0.f;
    cnts = mask ? 1.f : 0.f;
    stOut(out, 1 + rowg, mask ? sigf(lg) : 0.f, f32m);
    stOut(out, 1 + BS + rowg, mask ? tg : 0.f, f32m);
  }
  #pragma unroll
  for (int off=32; off>0; off>>=1){ bces += __shfl_down(bces, off); cnts += __shfl_down(cnts, off); }
  if ((t & 63) == 0 && t < 128){
    atomicAdd(&accum[0], bces);
    atomicAdd(&accum[1], cnts);
  }
}

__global__ void k_loss(const float* __restrict__ accum, void* __restrict__ out,
                       const int* __restrict__ flags){
  if (threadIdx.x == 0){
    float denom = fmaxf(accum[1], 1.f);
    stOut(out, 0, accum[0]/denom, flags[0]);
  }
}

extern "C" void kernel_launch(void* const* d_in, const int* in_sizes, int n_in,
                              void* d_out, int out_size, void* d_ws, size_t ws_size,
                              hipStream_t stream) {
  const int* q_data  = (const int*)d_in[0];
  const int* qa_data = (const int*)d_in[1];
  const void* target = d_in[2];
  const void* qW   = d_in[3];
  const void* qaW  = d_in[4];
  const void* keym = d_in[5];
  const void* initm= d_in[6];
  const void* eW   = d_in[7];
  const void* eb   = d_in[8];
  const void* aW   = d_in[9];
  const void* ab   = d_in[10];
  const void* rW   = d_in[11];
  const void* rb   = d_in[12];
  const void* pW   = d_in[13];
  const void* pb   = d_in[14];

  char* ws = (char*)d_ws;
  const size_t CW_OFF = 256;
  const size_t CW_BYTES = (size_t)BS*MEM*4;              // 65,536,000
  const size_t EA_OFF = CW_OFF + CW_BYTES;
  float* accum = (float*)ws;
  int* flags = (int*)(ws + 64);
  float* cw = (float*)(ws + CW_OFF);

  const long per_batch = (long)SEQ*(2*DV)*2 + (long)SEQ*DV*2;  // 768000 B per batch
  long rem = (long)ws_size - (long)EA_OFF;
  int bchunk = 512;
  while (bchunk > 32 && per_batch*bchunk > rem) bchunk >>= 1;  // 512,256,128,64,32

  const size_t EA_BYTES = (size_t)bchunk*SEQ*(2*DV)*2;
  unsigned short* ea = (unsigned short*)(ws + EA_OFF);
  unsigned short* rd = (unsigned short*)(ws + EA_OFF + EA_BYTES);

  k_detect<<<1, 64, 0, stream>>>((const unsigned short*)keym, qa_data, flags, accum);
  k_cw  <<<BS/256, 256, 0, stream>>>(q_data, qW, keym, cw, flags);

  int nchunk = BATCH / bchunk;
  for (int c = 0; c < nchunk; c++){
    long b0 = (long)c * bchunk;
    int rows = bchunk * SEQ;
    int nwg = (rows/128)*4;
    k_ea  <<<nwg, 256, 0, stream>>>(qa_data, b0*SEQ, qaW, eW, eb, aW, ab, ea, flags, nwg);
    k_scan<<<dim3(bchunk, 2), 512, 0, stream>>>(cw + b0*SEQ*MEM, ea, initm, rd, flags);
    k_pred<<<rows/128, 256, 0, stream>>>(q_data, b0*SEQ, qW, rd, rW, rb, pW, pb,
                                         target, d_out, accum, flags);
  }
  k_loss<<<1, 64, 0, stream>>>(accum, d_out, flags);
}

// Round 23
// 963.244 us; speedup vs baseline: 1.3080x; 1.3080x over previous
//
#include <hip/hip_runtime.h>
#include <hip/hip_bf16.h>

#define BATCH 512
#define SEQ   500
#define BS    (BATCH*SEQ)     // 256000
#define MEM   64
#define DK    128
#define DV    256
#define FC    128
#define KS    16              // scan steps per LDS stage

typedef float f32x4 __attribute__((ext_vector_type(4)));
typedef float f32x2 __attribute__((ext_vector_type(2)));
typedef unsigned int u32x4 __attribute__((ext_vector_type(4)));
typedef unsigned int u32x2 __attribute__((ext_vector_type(2)));
typedef unsigned short u16x8 __attribute__((ext_vector_type(8)));
typedef __bf16 bf16x8 __attribute__((ext_vector_type(8)));

__device__ __forceinline__ float bf2f(unsigned short u){ return __uint_as_float(((unsigned)u)<<16); }
__device__ __forceinline__ unsigned short f2bfu(float x){
  unsigned u = __float_as_uint(x);
  return (unsigned short)((u + 0x7FFFu + ((u>>16)&1u)) >> 16);  // RNE
}
__device__ __forceinline__ float sigf(float x){ return 1.f/(1.f+__expf(-x)); }
__device__ __forceinline__ float tanh_fast(float x){ return 2.f/(1.f+__expf(-2.f*x)) - 1.f; }

// 3-hop in-row shift-add: after shr 1,2,4 lane q==7 holds its 8-lane group sum.
#define DPP3(r) { \
  asm("v_add_f32_dpp %0, %0, %0 row_shr:1 row_mask:0xf bank_mask:0xf bound_ctrl:0" : "+v"(r)); \
  asm("v_add_f32_dpp %0, %0, %0 row_shr:2 row_mask:0xf bank_mask:0xf bound_ctrl:0" : "+v"(r)); \
  asm("v_add_f32_dpp %0, %0, %0 row_shr:4 row_mask:0xf bank_mask:0xf bound_ctrl:0" : "+v"(r)); \
}

__device__ __forceinline__ float ldF(const void* p, long i, int f32m){
  return f32m ? ((const float*)p)[i] : bf2f(((const unsigned short*)p)[i]);
}
__device__ __forceinline__ int ldI(const int* p, long i, int i64m){
  return i64m ? p[2*i] : p[i];   // little-endian low word of int64
}
__device__ __forceinline__ void st8(unsigned short* dst, const void* src, long i, int f32m){
  if (f32m){
    const float* q = (const float*)src + i;
    f32x4 a = *(const f32x4*)q;
    f32x4 b = *(const f32x4*)(q+4);
    u16x8 o;
    o[0]=f2bfu(a[0]); o[1]=f2bfu(a[1]); o[2]=f2bfu(a[2]); o[3]=f2bfu(a[3]);
    o[4]=f2bfu(b[0]); o[5]=f2bfu(b[1]); o[6]=f2bfu(b[2]); o[7]=f2bfu(b[3]);
    *(u16x8*)dst = o;
  } else {
    *(u16x8*)dst = *(const u16x8*)((const unsigned short*)src + i);
  }
}
__device__ __forceinline__ void stOut(void* p, long i, float x, int f32m){
  if (f32m) ((float*)p)[i] = x;
  else ((unsigned short*)p)[i] = f2bfu(x);
}

// ---------------- K0: dtype detection + accum zero ----------------
__global__ void k_detect(const unsigned short* __restrict__ km, const int* __restrict__ qa,
                         int* __restrict__ flags, float* __restrict__ accum){
  int t = threadIdx.x;            // 64 threads, one wave
  if (t < 2) accum[t] = 0.f;
  unsigned short u = km[2*t];     // even u16 halves of key_memory
  int e = (u >> 7) & 0xFF;
  bool sane = (e==0) || (e>=100 && e<=140);
  unsigned long long sm = __ballot(sane);
  unsigned long long zm = __ballot(qa[2*t+1] == 0);
  if (t == 0){
    flags[0] = (__popcll(sm) < 48) ? 1 : 0;               // 1 = f32 float buffers
    flags[1] = (zm == 0xFFFFFFFFFFFFFFFFull) ? 1 : 0;     // 1 = int64 index buffers
  }
}

// ---------------- K1: cw = softmax(q_e @ key^T) ----------------
__global__ __launch_bounds__(256, 2) void k_cw(const int* __restrict__ qd,
    const void* __restrict__ qW, const void* __restrict__ keym,
    float* __restrict__ cw, const int* __restrict__ flags){
  const int f32m = flags[0], i64m = flags[1];
  __shared__ float keyT[DK][MEM];
  int t = threadIdx.x;
  for (int i=t;i<MEM*DK;i+=256){ int m=i&63, k=i>>6; keyT[k][m] = ldF(keym, (long)m*DK+k, f32m); }
  __syncthreads();
  long row = (long)blockIdx.x*256 + t;
  int qid = ldI(qd, row, i64m);
  long qb = (long)qid*DK;
  f32x4 A[16];
  #pragma unroll
  for (int g=0;g<16;g++) A[g] = (f32x4){0.f,0.f,0.f,0.f};
  for (int kk=0;kk<DK;kk+=8){
    float qv[8];
    if (f32m){
      const float* qp = (const float*)qW + qb + kk;
      f32x4 a=*(const f32x4*)qp, b=*(const f32x4*)(qp+4);
      qv[0]=a[0];qv[1]=a[1];qv[2]=a[2];qv[3]=a[3];qv[4]=b[0];qv[5]=b[1];qv[6]=b[2];qv[7]=b[3];
    } else {
      u16x8 u = *(const u16x8*)((const unsigned short*)qW + qb + kk);
      #pragma unroll
      for (int j=0;j<8;j++) qv[j]=bf2f(u[j]);
    }
    #pragma unroll
    for (int j=0;j<8;j++){
      float q = qv[j];
      #pragma unroll
      for (int g=0;g<16;g++){
        f32x4 kv = *(const f32x4*)&keyT[kk+j][g*4];
        f32x4 a = A[g];
        a[0]=fmaf(q,kv[0],a[0]); a[1]=fmaf(q,kv[1],a[1]);
        a[2]=fmaf(q,kv[2],a[2]); a[3]=fmaf(q,kv[3],a[3]);
        A[g]=a;
      }
    }
  }
  float mx = -1e30f;
  #pragma unroll
  for (int g=0;g<16;g++){
    f32x4 a = A[g];
    mx = fmaxf(mx, fmaxf(fmaxf(a[0],a[1]), fmaxf(a[2],a[3])));
  }
  float sum = 0.f;
  #pragma unroll
  for (int g=0;g<16;g++){
    f32x4 a = A[g];
    a[0]=__expf(a[0]-mx); a[1]=__expf(a[1]-mx); a[2]=__expf(a[2]-mx); a[3]=__expf(a[3]-mx);
    sum += (a[0]+a[1])+(a[2]+a[3]);
    A[g]=a;
  }
  float inv = 1.f/sum;
  float* outp = cw + row*MEM;
  #pragma unroll
  for (int g=0;g<16;g++){
    f32x4 a = A[g];
    f32x4 v = { a[0]*inv, a[1]*inv, a[2]*inv, a[3]*inv };
    *(f32x4*)(outp + g*4) = v;
  }
}

// ---------------- K2 (per-chunk): [erase|add] GEMM, 128x(er64|ad64) pair-blocks ----------------
// r15 measured-best: (256,2), 21KB LDS, bijective XCD-chunk swizzle, VGPR 56, occ 44%
__global__ __launch_bounds__(256, 2) void k_ea(const int* __restrict__ qad, long row0,
    const void* __restrict__ qaW, const void* __restrict__ eW, const void* __restrict__ ebias,
    const void* __restrict__ aW, const void* __restrict__ abias,
    unsigned short* __restrict__ ea, const int* __restrict__ flags, int nwg){
  const int f32m = flags[0], i64m = flags[1];
  __shared__ unsigned short As[128][40];
  __shared__ unsigned short Bs[128][40];   // rows 0..63 = eW[64bn+r], 64..127 = aW[64bn+r-64]
  __shared__ int rid[128];
  int g = blockIdx.x;
  int x = g & 7, idx = g >> 3;
  int qq = nwg >> 3, rr = nwg & 7;
  int base = (x < rr) ? x*(qq+1) : rr*(qq+1) + (x-rr)*qq;
  int orig = base + idx;
  int bm = orig >> 2, bn = orig & 3;

  int t = threadIdx.x;
  if (t < 128) rid[t] = ldI(qad, row0 + (long)bm*128 + t, i64m);
  int lane = t & 63, wid = t >> 6;
  int wr = wid >> 1, wc = wid & 1;
  f32x4 acc[4][4] = {};
  for (int k0=0;k0<DV;k0+=32){
    __syncthreads();
    #pragma unroll
    for (int j=0;j<2;j++){
      int c = t*2+j, r = c>>2, ko = (c&3)*8;
      st8(&As[r][ko], qaW, (long)rid[r]*DV + k0 + ko, f32m);
      if (r < 64) st8(&Bs[r][ko], eW, (long)(64*bn + r)*DV + k0 + ko, f32m);
      else        st8(&Bs[r][ko], aW, (long)(64*bn + r - 64)*DV + k0 + ko, f32m);
    }
    __syncthreads();
    bf16x8 af[4], bfr[4];
    #pragma unroll
    for (int i=0;i<4;i++){
      af[i]  = __builtin_bit_cast(bf16x8, *(const u16x8*)&As[wr*64+i*16+(lane&15)][(lane>>4)*8]);
      bfr[i] = __builtin_bit_cast(bf16x8, *(const u16x8*)&Bs[wc*64+i*16+(lane&15)][(lane>>4)*8]);
    }
    #pragma unroll
    for (int i=0;i<4;i++)
      #pragma unroll
      for (int n=0;n<4;n++)
        acc[i][n] = __builtin_amdgcn_mfma_f32_16x16x32_bf16(af[i], bfr[n], acc[i][n],0,0,0);
  }
  #pragma unroll
  for (int i=0;i<4;i++)
    #pragma unroll
    for (int n=0;n<4;n++){
      int cc = n*16 + (lane&15);          // col within the 64-wide strip
      int gcol = 64*bn + cc;              // global er/ad column
      float bias = wc ? ldF(abias,gcol,f32m) : ldF(ebias,gcol,f32m);
      int dcol = 2*gcol + wc;             // interleaved (er,ad) pair layout
      #pragma unroll
      for (int rix=0;rix<4;rix++){
        long rowg = (long)bm*128 + wr*64 + i*16 + (lane>>4)*4 + rix;
        float v = acc[i][n][rix] + bias;
        float o = wc ? tanh_fast(v) : sigf(v);
        ea[rowg*(2*DV) + dcol] = f2bfu(o);
      }
    }
}

// ---------------- K3 (per-chunk): scan — d-half split, LDS-staged, scalar FMA + DPP ----------------
// r17 measured-best (210 µs): grid (bchunk, 2), 512 thr
#define SCAN_STEP2(srel) { \
  f32x4 W0 = *(const f32x4*)(wb + (srel)*MEM); \
  f32x4 W1 = *(const f32x4*)(wb + (srel)*MEM + 4); \
  u32x2 uu = *(const u32x2*)(eb + (srel)*128); \
  float er0 = __uint_as_float(uu[0] << 16); \
  float ad0 = __uint_as_float(uu[0] & 0xFFFF0000u); \
  float er1 = __uint_as_float(uu[1] << 16); \
  float ad1 = __uint_as_float(uu[1] & 0xFFFF0000u); \
  float ra0=0.f, ra1=0.f, rb0=0.f, rb1=0.f; \
  _Pragma("unroll") \
  for (int j=0; j<8; j++){ \
    float w = (j<4) ? W0[j] : W1[j-4]; \
    if (j & 1) ra1 = fmaf(w, MA[j], ra1); else ra0 = fmaf(w, MA[j], ra0); \
    float ta = fmaf(MA[j], er0, -ad0); \
    MA[j] = fmaf(-w, ta, MA[j]); \
    if (j & 1) rb1 = fmaf(w, MB[j], rb1); else rb0 = fmaf(w, MB[j], rb0); \
    float tb = fmaf(MB[j], er1, -ad1); \
    MB[j] = fmaf(-w, tb, MB[j]); \
  } \
  float r0 = ra0 + ra1; \
  float r1 = rb0 + rb1; \
  DPP3(r0); \
  DPP3(r1); \
  if (q == 7){ \
    unsigned pk; \
    asm("v_cvt_pk_bf16_f32 %0, %1, %2" : "=v"(pk) : "v"(r0), "v"(r1)); \
    rdu[(srel)*128] = pk; \
  } \
}

__global__ __launch_bounds__(512, 4) void k_scan(const float* __restrict__ cw,
    const unsigned short* __restrict__ ea, const void* __restrict__ initm,
    unsigned short* __restrict__ rdout, const int* __restrict__ flags){
  const int f32m = flags[0];
  __shared__ float        w_lds[2][KS][MEM];     // 8 KB
  __shared__ unsigned int ea_lds[2][KS][128];    // 16 KB (this block's d-half)
  int b = blockIdx.x, y = blockIdx.y;
  int t = threadIdx.x;          // 0..511
  int q = t & 7;
  int dp = t >> 3;              // 0..63
  int d0 = y*128 + 2*dp;
  int m0 = q * 8;

  float MA[8], MB[8];
  #pragma unroll
  for (int g=0; g<8; g++){
    MA[g] = ldF(initm, (long)(m0+g)*DV + d0,   f32m);
    MB[g] = ldF(initm, (long)(m0+g)*DV + d0+1, f32m);
  }

  const float* cwb = cw + (long)b*SEQ*MEM;
  const unsigned int* epb = (const unsigned int*)(ea + (long)b*SEQ*(2*DV)) + y*128;  // row stride 256 u32
  unsigned int* rdu = (unsigned int*)(rdout + (long)b*SEQ*DV) + y*64 + dp;           // row = 128 u32

  {
    f32x2 wreg = *(const f32x2*)(cwb + 2*t);
    u32x4 ereg = *(const u32x4*)(epb + (t>>5)*256 + 4*(t&31));
    ((f32x2*)(&w_lds[0][0][0]))[t] = wreg;
    ((u32x4*)(&ea_lds[0][0][0]))[t] = ereg;
  }
  __syncthreads();

  int cur = 0;
  for (int st = 0; st < 31; st++){
    f32x2 wnext = *(const f32x2*)(cwb + (st+1)*KS*MEM + 2*t);
    u32x4 enext = *(const u32x4*)(epb + ((st+1)*KS + (t>>5))*256 + 4*(t&31));

    const float* wb        = &w_lds[cur][0][0] + m0;
    const unsigned int* eb = &ea_lds[cur][0][0] + 2*dp;
    #pragma unroll
    for (int srel=0; srel<KS; srel++){
      SCAN_STEP2(srel);
    }
    ((f32x2*)(&w_lds[cur^1][0][0]))[t] = wnext;
    ((u32x4*)(&ea_lds[cur^1][0][0]))[t] = enext;
    rdu += KS*128;
    __syncthreads();
    cur ^= 1;
  }
  {
    const float* wb        = &w_lds[cur][0][0] + m0;
    const unsigned int* eb = &ea_lds[cur][0][0] + 2*dp;
    #pragma unroll
    for (int srel=0; srel<4; srel++){
      SCAN_STEP2(srel);
    }
  }
}

// ---------------- K4 (per-chunk): h = tanh([reads|q_e] @ rW^T + rb); logit; BCE ----------------
// r15 measured-best: separate As/Bs/hs, (256,2)
__global__ __launch_bounds__(256, 2) void k_pred(const int* __restrict__ qd, long row0,
    const void* __restrict__ qW, const unsigned short* __restrict__ rds,
    const void* __restrict__ rW, const void* __restrict__ rb,
    const void* __restrict__ pW, const void* __restrict__ pb,
    const void* __restrict__ target,
    void* __restrict__ out, float* __restrict__ accum,
    const int* __restrict__ flags){
  const int f32m = flags[0], i64m = flags[1];
  __shared__ unsigned short As[128][40];
  __shared__ unsigned short Bs[128][40];
  __shared__ unsigned short hs[128][136];
  __shared__ int rid[128];
  int t = threadIdx.x;
  int bm = blockIdx.x;
  if (t<128) rid[t] = ldI(qd, row0 + (long)bm*128+t, i64m);
  int lane=t&63, wid=t>>6, wr=wid>>1, wc=wid&1;
  f32x4 acc[4][4] = {};
  for (int k0=0;k0<(DV+DK);k0+=32){
    __syncthreads();
    #pragma unroll
    for (int j=0;j<2;j++){
      int c=t*2+j, r=c>>2, ko=(c&3)*8;
      if (k0 < DV) st8(&As[r][ko], rds, ((long)bm*128+r)*DV + k0+ko, 0);
      else         st8(&As[r][ko], qW, (long)rid[r]*DK + (k0-DV)+ko, f32m);
      st8(&Bs[r][ko], rW, (long)r*(DV+DK) + k0+ko, f32m);
    }
    __syncthreads();
    bf16x8 af[4], bfr[4];
    #pragma unroll
    for (int i=0;i<4;i++){
      af[i]  = __builtin_bit_cast(bf16x8, *(const u16x8*)&As[wr*64+i*16+(lane&15)][(lane>>4)*8]);
      bfr[i] = __builtin_bit_cast(bf16x8, *(const u16x8*)&Bs[wc*64+i*16+(lane&15)][(lane>>4)*8]);
    }
    #pragma unroll
    for (int i=0;i<4;i++)
      #pragma unroll
      for (int n=0;n<4;n++)
        acc[i][n] = __builtin_amdgcn_mfma_f32_16x16x32_bf16(af[i], bfr[n], acc[i][n],0,0,0);
  }
  #pragma unroll
  for (int i=0;i<4;i++)
    #pragma unroll
    for (int n=0;n<4;n++){
      int col = wc*64 + n*16 + (lane&15);
      float bias = ldF(rb, col, f32m);
      #pragma unroll
      for (int rix=0;rix<4;rix++){
        int rowl = wr*64 + i*16 + (lane>>4)*4 + rix;
        hs[rowl][col] = f2bfu(tanh_fast(acc[i][n][rix] + bias));
      }
    }
  __syncthreads();
  float bces = 0.f, cnts = 0.f;
  if (t < 128){
    float lg = ldF(pb, 0, f32m);
    #pragma unroll
    for (int cc=0;cc<FC;cc++) lg = fmaf(bf2f(hs[t][cc]), ldF(pW, cc, f32m), lg);
    long rowg = row0 + (long)bm*128 + t;
    float tg = ldF(target, rowg, f32m);
    bool mask = tg >= 0.f;
    float e = __expf(-fabsf(lg));
    float bce = fmaxf(lg, 0.f) - lg*tg + __logf(1.f + e);
    bces = mask ? bce : 0.f;
    cnts = mask ? 1.f : 0.f;
    stOut(out, 1 + rowg, mask ? sigf(lg) : 0.f, f32m);
    stOut(out, 1 + BS + rowg, mask ? tg : 0.f, f32m);
  }
  #pragma unroll
  for (int off=32; off>0; off>>=1){ bces += __shfl_down(bces, off); cnts += __shfl_down(cnts, off); }
  if ((t & 63) == 0 && t < 128){
    atomicAdd(&accum[0], bces);
    atomicAdd(&accum[1], cnts);
  }
}

__global__ void k_loss(const float* __restrict__ accum, void* __restrict__ out,
                       const int* __restrict__ flags){
  if (threadIdx.x == 0){
    float denom = fmaxf(accum[1], 1.f);
    stOut(out, 0, accum[0]/denom, flags[0]);
  }
}

extern "C" void kernel_launch(void* const* d_in, const int* in_sizes, int n_in,
                              void* d_out, int out_size, void* d_ws, size_t ws_size,
                              hipStream_t stream) {
  const int* q_data  = (const int*)d_in[0];
  const int* qa_data = (const int*)d_in[1];
  const void* target = d_in[2];
  const void* qW   = d_in[3];
  const void* qaW  = d_in[4];
  const void* keym = d_in[5];
  const void* initm= d_in[6];
  const void* eW   = d_in[7];
  const void* eb   = d_in[8];
  const void* aW   = d_in[9];
  const void* ab   = d_in[10];
  const void* rW   = d_in[11];
  const void* rb   = d_in[12];
  const void* pW   = d_in[13];
  const void* pb   = d_in[14];

  char* ws = (char*)d_ws;
  const size_t CW_OFF = 256;
  const size_t CW_BYTES = (size_t)BS*MEM*4;              // 65,536,000
  const size_t EA_OFF = CW_OFF + CW_BYTES;
  float* accum = (float*)ws;
  int* flags = (int*)(ws + 64);
  float* cw = (float*)(ws + CW_OFF);

  const long per_batch = (long)SEQ*(2*DV)*2 + (long)SEQ*DV*2;  // 768000 B per batch
  long rem = (long)ws_size - (long)EA_OFF;
  int bchunk = 512;
  while (bchunk > 32 && per_batch*bchunk > rem) bchunk >>= 1;  // 512,256,128,64,32

  const size_t EA_BYTES = (size_t)bchunk*SEQ*(2*DV)*2;
  unsigned short* ea = (unsigned short*)(ws + EA_OFF);
  unsigned short* rd = (unsigned short*)(ws + EA_OFF + EA_BYTES);

  k_detect<<<1, 64, 0, stream>>>((const unsigned short*)keym, qa_data, flags, accum);
  k_cw  <<<BS/256, 256, 0, stream>>>(q_data, qW, keym, cw, flags);

  int nchunk = BATCH / bchunk;
  for (int c = 0; c < nchunk; c++){
    long b0 = (long)c * bchunk;
    int rows = bchunk * SEQ;
    int nwg = (rows/128)*4;
    k_ea  <<<nwg, 256, 0, stream>>>(qa_data, b0*SEQ, qaW, eW, eb, aW, ab, ea, flags, nwg);
    k_scan<<<dim3(bchunk, 2), 512, 0, stream>>>(cw + b0*SEQ*MEM, ea, initm, rd, flags);
    k_pred<<<rows/128, 256, 0, stream>>>(q_data, b0*SEQ, qW, rd, rW, rb, pW, pb,
                                         target, d_out, accum, flags);
  }
  k_loss<<<1, 64, 0, stream>>>(accum, d_out, flags);
}